// Round 7
// baseline (43.460 us; speedup 1.0000x reference)
//
#include <hip/hip_runtime.h>

#define MARGIN 0.2f
#define EPSF   1e-16f

constexpr int BSZ = 512;   // batch
constexpr int DIM = 1024;  // embedding dim

typedef __attribute__((ext_vector_type(8))) short    bf16x8;
typedef __attribute__((ext_vector_type(4))) unsigned uint4v;
typedef __attribute__((ext_vector_type(4))) float    f32x4;

// 8x f32 -> 8x bf16 via v_cvt_pk_bf16_f32 (RNE). A and B use the same packing;
// dot products are k-permutation invariant, so in-lane order is free.
__device__ __forceinline__ bf16x8 cvt8(float4 a, float4 b) {
    uint4v u;
    asm("v_cvt_pk_bf16_f32 %0, %1, %2" : "=v"(u[0]) : "v"(a.x), "v"(a.y));
    asm("v_cvt_pk_bf16_f32 %0, %1, %2" : "=v"(u[1]) : "v"(a.z), "v"(a.w));
    asm("v_cvt_pk_bf16_f32 %0, %1, %2" : "=v"(u[2]) : "v"(b.x), "v"(b.y));
    asm("v_cvt_pk_bf16_f32 %0, %1, %2" : "=v"(u[3]) : "v"(b.z), "v"(b.w));
    return __builtin_bit_cast(bf16x8, u);
}

// ---------------- Node 1: MFMA GEMM, K split across wave pairs --------------
// 256 blocks x 8 waves. Wave w: tile tw = w&3 (tile = blk*4 + tw), K-half
// kh = w>>2. Waves (tw) and (tw+4) compute the same 16x16 tile over K halves;
// partials combined via LDS. Also zeroes the global accumulators (block 0).
// mfma_f32_16x16x32_bf16: A/B row|col = lane&15, k = (lane>>4)*8 + j;
// C/D: col = lane&15, row = (lane>>4)*4 + q.
__global__ void __launch_bounds__(512, 4) gemm_half(const float* __restrict__ I,
                                                    const float* __restrict__ S,
                                                    float* __restrict__ pw,
                                                    float* __restrict__ acc,
                                                    unsigned* __restrict__ ctr) {
    __shared__ f32x4 part[4][64];

    const int tid  = threadIdx.x;
    const int lane = tid & 63;
    const int w    = tid >> 6;
    const int tw   = w & 3;
    const int kh   = w >> 2;                 // K half: 0 or 1

    if (blockIdx.x == 0 && tid == 0) { acc[0] = 0.f; acc[1] = 0.f; *ctr = 0u; }

    const int tile = blockIdx.x * 4 + tw;    // 0..1023 over 32x32 tile grid
    const int tr   = (tile >> 5) * 16;
    const int tc   = (tile & 31) * 16;
    const int r    = lane & 15;
    const int ko   = (lane >> 4) * 8;

    const float* Ab = I + (size_t)(tr + r) * DIM + kh * 512 + ko;
    const float* Bb = S + (size_t)(tc + r) * DIM + kh * 512 + ko;

    f32x4 acc0 = {0.f, 0.f, 0.f, 0.f};
    f32x4 acc1 = {0.f, 0.f, 0.f, 0.f};
#pragma unroll
    for (int t = 0; t < 16; t += 2) {        // 16 k-steps (K=512), 2 chains
        acc0 = __builtin_amdgcn_mfma_f32_16x16x32_bf16(
                   cvt8(*(const float4*)(Ab + t * 32),      *(const float4*)(Ab + t * 32 + 4)),
                   cvt8(*(const float4*)(Bb + t * 32),      *(const float4*)(Bb + t * 32 + 4)),
                   acc0, 0, 0, 0);
        acc1 = __builtin_amdgcn_mfma_f32_16x16x32_bf16(
                   cvt8(*(const float4*)(Ab + t * 32 + 32), *(const float4*)(Ab + t * 32 + 36)),
                   cvt8(*(const float4*)(Bb + t * 32 + 32), *(const float4*)(Bb + t * 32 + 36)),
                   acc1, 0, 0, 0);
    }
    acc0 += acc1;

    if (kh == 1) part[tw][lane] = acc0;
    __syncthreads();
    if (kh == 0) {
        acc0 += part[tw][lane];
        const int orow = tr + (lane >> 4) * 4;
        const int ocol = tc + r;
#pragma unroll
        for (int q = 0; q < 4; ++q)
            pw[(orow + q) * BSZ + ocol] = acc0[q];
    }
}

// ---------------- Node 2: masked triplet reduce + last-block finalize -------
// 512 blocks x 256 thr, one block per anchor.
__global__ void __launch_bounds__(256) triplet_reduce(const float* __restrict__ pw,
                                                      const int*   __restrict__ labels,
                                                      float* __restrict__ acc,
                                                      unsigned* __restrict__ ctr,
                                                      float* __restrict__ out) {
    __shared__ float pwrow[BSZ];
    __shared__ int   lab[BSZ];
    __shared__ int   poslist[BSZ];
    __shared__ int   npos_sh;
    __shared__ float wsum[4];
    __shared__ int   wcnt[4];

    const int a   = blockIdx.x;
    const int tid = threadIdx.x;

    if (tid == 0) npos_sh = 0;
    if (tid < 128) {                          // vectorized stage: 2 KB + 2 KB
        ((float4*)pwrow)[tid] = ((const float4*)(pw + (size_t)a * BSZ))[tid];
        ((int4*)lab)[tid]     = ((const int4*)labels)[tid];
    }
    __syncthreads();

    const int la = lab[a];
    for (int p = tid; p < BSZ; p += 256) {
        if (lab[p] == la) {
            int idx = atomicAdd(&npos_sh, 1);
            poslist[idx] = p;
        }
    }
    __syncthreads();
    const int npos = npos_sh;

    float sum = 0.f;
    int   cnt = 0;
    for (int n = tid; n < BSZ; n += 256) {
        if (lab[n] != la) {
            const float pn = pwrow[n];
            for (int i = 0; i < npos; ++i) {
                const float v = pwrow[poslist[i]] - pn + MARGIN;
                sum += fmaxf(v, 0.f);
                cnt += (v > EPSF) ? 1 : 0;
            }
        }
    }

#pragma unroll
    for (int off = 32; off > 0; off >>= 1) {
        sum += __shfl_down(sum, off);
        cnt += __shfl_down(cnt, off);
    }
    const int wid = tid >> 6, lane = tid & 63;
    if (lane == 0) { wsum[wid] = sum; wcnt[wid] = cnt; }
    __syncthreads();

    if (tid == 0) {
        const float s = wsum[0] + wsum[1] + wsum[2] + wsum[3];
        const float c = (float)(wcnt[0] + wcnt[1] + wcnt[2] + wcnt[3]);
        atomicAdd(&acc[0], s);
        atomicAdd(&acc[1], c);
        __threadfence();
        const unsigned old = atomicAdd(ctr, 1u);
        if (old == (unsigned)(BSZ - 1)) {     // last of 512 blocks
            const float S_ = atomicAdd(&acc[0], 0.f);   // coherent RMW read
            const float C_ = atomicAdd(&acc[1], 0.f);
            out[0] = S_ / (C_ + EPSF);
        }
    }
}

extern "C" void kernel_launch(void* const* d_in, const int* in_sizes, int n_in,
                              void* d_out, int out_size, void* d_ws, size_t ws_size,
                              hipStream_t stream) {
    const int*   labels = (const int*)d_in[0];
    const float* img    = (const float*)d_in[1];
    const float* sen    = (const float*)d_in[2];
    float* out = (float*)d_out;

    // ws layout: acc (8 B), ctr (4 B), pw (1 MB). acc/ctr zeroed by gemm_half.
    float*    acc = (float*)d_ws;
    unsigned* ctr = (unsigned*)((char*)d_ws + 8);
    float*    pw  = (float*)((char*)d_ws + 256);

    gemm_half<<<256, 512, 0, stream>>>(img, sen, pw, acc, ctr);
    triplet_reduce<<<BSZ, 256, 0, stream>>>(pw, labels, acc, ctr, out);
}

// Round 8
// 26.631 us; speedup vs baseline: 1.6319x; 1.6319x over previous
//
#include <hip/hip_runtime.h>

#define MARGIN 0.2f
#define EPSF   1e-16f

constexpr int BSZ = 512;   // batch
constexpr int DIM = 1024;  // embedding dim

typedef __attribute__((ext_vector_type(8))) short    bf16x8;
typedef __attribute__((ext_vector_type(4))) unsigned uint4v;
typedef __attribute__((ext_vector_type(4))) float    f32x4;

// 8x f32 -> 8x bf16 via v_cvt_pk_bf16_f32 (RNE). A and B use the same packing;
// dot products are k-permutation invariant, so in-lane order is free.
__device__ __forceinline__ bf16x8 cvt8(float4 a, float4 b) {
    uint4v u;
    asm("v_cvt_pk_bf16_f32 %0, %1, %2" : "=v"(u[0]) : "v"(a.x), "v"(a.y));
    asm("v_cvt_pk_bf16_f32 %0, %1, %2" : "=v"(u[1]) : "v"(a.z), "v"(a.w));
    asm("v_cvt_pk_bf16_f32 %0, %1, %2" : "=v"(u[2]) : "v"(b.x), "v"(b.y));
    asm("v_cvt_pk_bf16_f32 %0, %1, %2" : "=v"(u[3]) : "v"(b.z), "v"(b.w));
    return __builtin_bit_cast(bf16x8, u);
}

// ---------------- Node 1: MFMA GEMM, one 16x16 tile/block, K split 4 ways ----
// 1024 blocks x 4 waves. Wave w covers k in [w*256, w*256+256): 8 k-steps.
// Wave 0 combines partials via LDS (fixed order: w0 + p1 + p2 + p3) and
// stores. XCD-bijective tile swizzle: xcd = bid&7 gets tiles [xcd*128, +128)
// = 4 contiguous row-strips -> A-reads 256 KB + B 2 MB per XCD (L2-resident).
// mfma_f32_16x16x32_bf16: A/B row|col = lane&15, k = (lane>>4)*8 + j;
// C/D: col = lane&15, row = (lane>>4)*4 + q.
__global__ void __launch_bounds__(256) mfma_gemm(const float* __restrict__ I,
                                                 const float* __restrict__ S,
                                                 float* __restrict__ pw) {
    __shared__ f32x4 part[3][64];

    const int tid  = threadIdx.x;
    const int lane = tid & 63;
    const int w    = tid >> 6;                       // K quarter 0..3
    const int tile = ((blockIdx.x & 7) << 7) | (blockIdx.x >> 3);  // bijective
    const int tr   = (tile >> 5) * 16;               // anchor base
    const int tc   = (tile & 31) * 16;               // negative base
    const int r    = lane & 15;
    const int ko   = (lane >> 4) * 8;

    const float* Ab = I + (size_t)(tr + r) * DIM + w * 256 + ko;
    const float* Bb = S + (size_t)(tc + r) * DIM + w * 256 + ko;

    f32x4 acc0 = {0.f, 0.f, 0.f, 0.f};
    f32x4 acc1 = {0.f, 0.f, 0.f, 0.f};
#pragma unroll
    for (int t = 0; t < 8; t += 2) {                 // 8 k-steps, 2 acc chains
        acc0 = __builtin_amdgcn_mfma_f32_16x16x32_bf16(
                   cvt8(*(const float4*)(Ab + t * 32),      *(const float4*)(Ab + t * 32 + 4)),
                   cvt8(*(const float4*)(Bb + t * 32),      *(const float4*)(Bb + t * 32 + 4)),
                   acc0, 0, 0, 0);
        acc1 = __builtin_amdgcn_mfma_f32_16x16x32_bf16(
                   cvt8(*(const float4*)(Ab + t * 32 + 32), *(const float4*)(Ab + t * 32 + 36)),
                   cvt8(*(const float4*)(Bb + t * 32 + 32), *(const float4*)(Bb + t * 32 + 36)),
                   acc1, 0, 0, 0);
    }
    acc0 += acc1;

    if (w) part[w - 1][lane] = acc0;
    __syncthreads();
    if (w == 0) {
        acc0 += part[0][lane];
        acc0 += part[1][lane];
        acc0 += part[2][lane];
        const int orow = tr + (lane >> 4) * 4;
        const int ocol = tc + r;
#pragma unroll
        for (int q = 0; q < 4; ++q)
            pw[(orow + q) * BSZ + ocol] = acc0[q];
    }
}

// ---------------- Node 2: masked triplet reduction -> per-anchor partials ----
// One block (256 threads) per anchor a. Writes psum[a], pcnt[a] (no init).
__global__ void __launch_bounds__(256) triplet_reduce(const float* __restrict__ pw,
                                                      const int*   __restrict__ labels,
                                                      float* __restrict__ psum,
                                                      float* __restrict__ pcnt) {
    __shared__ float pwrow[BSZ];
    __shared__ int   lab[BSZ];
    __shared__ int   poslist[BSZ];
    __shared__ int   npos_sh;
    __shared__ float wsum[4];
    __shared__ int   wcnt[4];

    const int a   = blockIdx.x;
    const int tid = threadIdx.x;

    if (tid == 0) npos_sh = 0;
    for (int i = tid; i < BSZ; i += 256) {
        lab[i]   = labels[i];
        pwrow[i] = pw[a * BSZ + i];
    }
    __syncthreads();

    const int la = lab[a];
    for (int p = tid; p < BSZ; p += 256) {
        if (lab[p] == la) {
            int idx = atomicAdd(&npos_sh, 1);
            poslist[idx] = p;
        }
    }
    __syncthreads();
    const int npos = npos_sh;

    float sum = 0.f;
    int   cnt = 0;
    for (int n = tid; n < BSZ; n += 256) {
        if (lab[n] != la) {
            const float pn = pwrow[n];
            for (int i = 0; i < npos; ++i) {
                const float v = pwrow[poslist[i]] - pn + MARGIN;
                sum += fmaxf(v, 0.f);
                cnt += (v > EPSF) ? 1 : 0;
            }
        }
    }

#pragma unroll
    for (int off = 32; off > 0; off >>= 1) {
        sum += __shfl_down(sum, off);
        cnt += __shfl_down(cnt, off);
    }
    const int wid = tid >> 6, lane = tid & 63;
    if (lane == 0) { wsum[wid] = sum; wcnt[wid] = cnt; }
    __syncthreads();
    if (tid == 0) {
        psum[a] = wsum[0] + wsum[1] + wsum[2] + wsum[3];
        pcnt[a] = (float)(wcnt[0] + wcnt[1] + wcnt[2] + wcnt[3]);
    }
}

// ---------------- Node 3: finalize over 512 partials ----------------
__global__ void __launch_bounds__(512) finalize(const float* __restrict__ psum,
                                                const float* __restrict__ pcnt,
                                                float* __restrict__ out) {
    __shared__ float wsum[8], wcnt[8];
    const int tid = threadIdx.x;
    float s = psum[tid];
    float c = pcnt[tid];
#pragma unroll
    for (int off = 32; off > 0; off >>= 1) {
        s += __shfl_down(s, off);
        c += __shfl_down(c, off);
    }
    const int wid = tid >> 6, lane = tid & 63;
    if (lane == 0) { wsum[wid] = s; wcnt[wid] = c; }
    __syncthreads();
    if (tid == 0) {
        float S = 0.f, C = 0.f;
#pragma unroll
        for (int i = 0; i < 8; ++i) { S += wsum[i]; C += wcnt[i]; }
        out[0] = S / (C + EPSF);
    }
}

extern "C" void kernel_launch(void* const* d_in, const int* in_sizes, int n_in,
                              void* d_out, int out_size, void* d_ws, size_t ws_size,
                              hipStream_t stream) {
    const int*   labels = (const int*)d_in[0];
    const float* img    = (const float*)d_in[1];
    const float* sen    = (const float*)d_in[2];
    float* out = (float*)d_out;

    // workspace (all fully written every call -> no init needed)
    float* pw   = (float*)d_ws;                                  // 1 MB
    float* psum = (float*)((char*)d_ws + (1u << 20));            // 2 KB
    float* pcnt = (float*)((char*)d_ws + (1u << 20) + 2048);     // 2 KB

    mfma_gemm<<<1024, 256, 0, stream>>>(img, sen, pw);
    triplet_reduce<<<BSZ, 256, 0, stream>>>(pw, labels, psum, pcnt);
    finalize<<<1, 512, 0, stream>>>(psum, pcnt, out);
}